// Round 1
// baseline (162.081 us; speedup 1.0000x reference)
//
#include <hip/hip_runtime.h>
#include <stdint.h>
#include <stddef.h>

// Problem geometry (fixed by setup_inputs)
#define BROWS  16384   // inputs rows
#define SROWS  8192    // support vectors
#define FDIM   512     // features
#define NCHUNK 4       // S split for parallelism (grid = NCHUNK * 64 = 256 blocks)
#define SCHUNK (SROWS / NCHUNK)     // 2048
#define BN     32                   // support cols per tile
#define NTILES (SCHUNK / BN)        // 64
#define BM     256                  // X rows per block (8 waves * 32 rows)
#define KSTEPS (FDIM / 16)          // 32 MFMA k-steps of 16

#define LOG2E 1.44269504088896340736f

typedef __bf16 bf16x8 __attribute__((ext_vector_type(8)));
typedef float  f32x16 __attribute__((ext_vector_type(16)));

__device__ inline void gload16(const void* g, void* l) {
  __builtin_amdgcn_global_load_lds(
      (const __attribute__((address_space(1))) void*)g,
      (__attribute__((address_space(3))) void*)l, 16, 0, 0);
}

// ---------------------------------------------------------------------------
// Prep: S f32 -> bf16 (row major [SROWS][FDIM]), c2[s] = coeff[s]*exp(-g*||s||^2)
// one wave per row; norms computed from f32 originals.
// ---------------------------------------------------------------------------
__global__ __launch_bounds__(256) void prep_s_kernel(
    const float* __restrict__ S, const float* __restrict__ coeff,
    const float* __restrict__ gamma, __bf16* __restrict__ Sb,
    float* __restrict__ c2)
{
  const int lane = threadIdx.x & 63;
  const int wid  = threadIdx.x >> 6;
  const int row  = (blockIdx.x << 2) + wid;
  const float* src = S + ((size_t)row << 9) + (lane << 3);
  float4 a = ((const float4*)src)[0];
  float4 b = ((const float4*)src)[1];
  float sq = a.x*a.x + a.y*a.y + a.z*a.z + a.w*a.w +
             b.x*b.x + b.y*b.y + b.z*b.z + b.w*b.w;
  bf16x8 v;
  v[0]=(__bf16)a.x; v[1]=(__bf16)a.y; v[2]=(__bf16)a.z; v[3]=(__bf16)a.w;
  v[4]=(__bf16)b.x; v[5]=(__bf16)b.y; v[6]=(__bf16)b.z; v[7]=(__bf16)b.w;
  *(bf16x8*)(Sb + ((size_t)row << 9) + (lane << 3)) = v;
  #pragma unroll
  for (int m = 1; m < 64; m <<= 1) sq += __shfl_xor(sq, m, 64);
  if (lane == 0) {
    float g = gamma[0];
    c2[row] = coeff[row] * exp2f(-g * LOG2E * sq);
  }
}

// ---------------------------------------------------------------------------
// Main fused kernel.
// Block = 512 threads = 8 waves. Wave w owns X rows [m0+32w, m0+32w+32),
// full K=512 held in registers as bf16 fragments (converted on the fly;
// x_sq computed from f32 during the load).
// Loop over this block's S-chunk in 32-col tiles; B tile double-buffered in
// LDS, layout [kblock(64)][col(32)][8 bf16] -> conflict-free ds_read_b128
// with additive immediate offsets, and linear for global_load_lds staging.
// Epilogue folds exp into running per-row score. Partial per chunk -> ws.
// ---------------------------------------------------------------------------
__global__ __launch_bounds__(512, 2) void ocsvm_main_kernel(
    const float* __restrict__ X, const __bf16* __restrict__ Sb,
    const float* __restrict__ c2, const float* __restrict__ gamma,
    float* __restrict__ partials)
{
  __shared__ char lds[65536];   // 2 buffers * 32 KB
  const int tid  = threadIdx.x;
  const int wid  = tid >> 6;
  const int lane = tid & 63;
  const int col  = lane & 31;
  const int half = lane >> 5;

  // XCD-affine mapping: blocks on the same XCD (blockIdx % 8) share one
  // 2 MB S-chunk -> fits the 4 MB per-XCD L2.
  const int bx    = blockIdx.x;
  const int xcd   = bx & 7;
  const int grp   = bx >> 3;
  const int chunk = xcd >> 1;
  const int mtile = (grp << 1) + (xcd & 1);
  const int m0    = mtile * BM;
  const int chunk0 = chunk * SCHUNK;

  const float gam = gamma[0];
  const float K2  = 2.0f * gam * LOG2E;   // exp(2g*cross) = exp2(K2*cross)

  // ---------- A rows -> registers (bf16x8 frags), x_sq on the fly ----------
  // MFMA 32x32x16 A-frag: lane l -> row (l&31), k = 16*ks + 8*(l>>5) + [0..8)
  const int arow = m0 + (wid << 5) + col;
  const float* xp = X + ((size_t)arow << 9) + (half << 3);
  bf16x8 afrag[KSTEPS];
  float sq = 0.0f;
  #pragma unroll
  for (int ks = 0; ks < KSTEPS; ++ks) {
    float4 a = *(const float4*)(xp + (ks << 4));
    float4 b = *(const float4*)(xp + (ks << 4) + 4);
    sq += a.x*a.x + a.y*a.y + a.z*a.z + a.w*a.w +
          b.x*b.x + b.y*b.y + b.z*b.z + b.w*b.w;
    bf16x8 v;
    v[0]=(__bf16)a.x; v[1]=(__bf16)a.y; v[2]=(__bf16)a.z; v[3]=(__bf16)a.w;
    v[4]=(__bf16)b.x; v[5]=(__bf16)b.y; v[6]=(__bf16)b.z; v[7]=(__bf16)b.w;
    afrag[ks] = v;
  }
  sq += __shfl_xor(sq, 32, 64);            // lanes l, l^32 cover the full row
  const float e_x = exp2f(-gam * LOG2E * sq);

  // ---------- staging macro: 32 KB tile, 4 rounds of 512 threads * 16 B ----
  // linear LDS offset t_all*16 == [kb=t_all>>5][col=t_all&31][16B]
#define STAGE(bufsel, tile)                                                   \
  {                                                                           \
    _Pragma("unroll")                                                         \
    for (int r = 0; r < 4; ++r) {                                             \
      const int t_all = (r << 9) + tid;                                       \
      const int cs = t_all & 31;                                              \
      const int kb = t_all >> 5;                                              \
      const char* src = (const char*)Sb +                                     \
          (((size_t)(chunk0 + ((tile) << 5) + cs)) << 10) + (kb << 4);        \
      char* dst = &lds[((bufsel) << 15) + (((r << 9) + (wid << 6)) << 4)];    \
      gload16(src, dst);                                                      \
    }                                                                         \
  }

  STAGE(0, 0);
  __syncthreads();

  float scoreAcc[16];
  #pragma unroll
  for (int i = 0; i < 16; ++i) scoreAcc[i] = 0.0f;

  // B-frag read base: lane l -> col (l&31), k = 16*ks + 8*(l>>5) + [0..8)
  // LDS addr = (kblock*32 + col)*16, kblock = 2*ks + half  => base + ks*1024
  const char* bread0 = &lds[(half << 9) + (col << 4)];
  const float* c2p = c2 + chunk0 + col;

  for (int t = 0; t < NTILES; ++t) {
    if (t + 1 < NTILES) STAGE((t + 1) & 1, t + 1);

    const char* bb = bread0 + ((t & 1) << 15);
    f32x16 acc0 = {};
    f32x16 acc1 = {};
    #pragma unroll
    for (int ks = 0; ks < KSTEPS; ks += 2) {
      bf16x8 b0 = *(const bf16x8*)(bb + (ks << 10));
      bf16x8 b1 = *(const bf16x8*)(bb + ((ks + 1) << 10));
      acc0 = __builtin_amdgcn_mfma_f32_32x32x16_bf16(afrag[ks],     b0, acc0, 0, 0, 0);
      acc1 = __builtin_amdgcn_mfma_f32_32x32x16_bf16(afrag[ks + 1], b1, acc1, 0, 0, 0);
    }

    // epilogue: scoreAcc[r] += c2[s] * exp2(K2 * cross)
    const float c2v = c2p[t << 5];
    #pragma unroll
    for (int r2 = 0; r2 < 16; ++r2)
      scoreAcc[r2] += c2v * exp2f(K2 * (acc0[r2] + acc1[r2]));

    __syncthreads();   // staged tile ready; safe to overwrite read buffer next iter
  }

  // ---------- fold cols, apply e_x, write chunk partial ----------
  // C layout (m74/m101): col = lane&31, row = (reg&3) + 8*(reg>>2) + 4*half
  #pragma unroll
  for (int r2 = 0; r2 < 16; ++r2) {
    float v = scoreAcc[r2];
    v += __shfl_xor(v, 1, 64);
    v += __shfl_xor(v, 2, 64);
    v += __shfl_xor(v, 4, 64);
    v += __shfl_xor(v, 8, 64);
    v += __shfl_xor(v, 16, 64);
    const int rloc = (r2 & 3) + ((r2 >> 2) << 3) + (half << 2);
    const float exr = __shfl(e_x, rloc, 64);   // lane rloc holds row rloc's e_x
    if (col == 0)
      partials[chunk * BROWS + m0 + (wid << 5) + rloc] = exr * v;
  }
#undef STAGE
}

// ---------------------------------------------------------------------------
// Final: sum chunk partials, subtract rho.
// ---------------------------------------------------------------------------
__global__ __launch_bounds__(256) void reduce_kernel(
    const float* __restrict__ partials, const float* __restrict__ rho,
    float* __restrict__ out)
{
  const int i = blockIdx.x * 256 + threadIdx.x;
  float s = partials[i] + partials[BROWS + i] +
            partials[2 * BROWS + i] + partials[3 * BROWS + i];
  out[i] = s - rho[0];
}

extern "C" void kernel_launch(void* const* d_in, const int* in_sizes, int n_in,
                              void* d_out, int out_size, void* d_ws, size_t ws_size,
                              hipStream_t stream) {
  const float* X     = (const float*)d_in[0];   // [16384,512] f32
  const float* S     = (const float*)d_in[1];   // [8192,512]  f32
  const float* coeff = (const float*)d_in[2];   // [1,8192]    f32
  const float* rho   = (const float*)d_in[3];   // [1]         f32
  const float* gamma = (const float*)d_in[4];   // scalar      f32
  float* out = (float*)d_out;

  // ws layout: Sb bf16 (8 MB) | c2 (32 KB) | partials (256 KB)  ~= 8.7 MB
  char* ws = (char*)d_ws;
  __bf16* Sb      = (__bf16*)ws;
  float*  c2      = (float*)(ws + (size_t)SROWS * FDIM * 2);
  float*  parts   = (float*)(ws + (size_t)SROWS * FDIM * 2 + SROWS * 4);

  prep_s_kernel<<<SROWS / 4, 256, 0, stream>>>(S, coeff, gamma, Sb, c2);
  ocsvm_main_kernel<<<NCHUNK * 64, 512, 0, stream>>>(X, Sb, c2, gamma, parts);
  reduce_kernel<<<BROWS / 256, 256, 0, stream>>>(parts, rho, out);
}